// Round 2
// baseline (295.261 us; speedup 1.0000x reference)
//
#include <hip/hip_runtime.h>
#include <math.h>

namespace {

typedef float f32x4 __attribute__((ext_vector_type(4)));

__device__ __forceinline__ float rcp_f(float x) { return __builtin_amdgcn_rcpf(x); }

// z/(exp(z)-1), with 1 - z/2 for |z| < 1e-4 (matches reference efun)
__device__ __forceinline__ float efun(float z) {
    float e = __expf(z);
    float big = z * rcp_f(e - 1.0f);
    float small = 1.0f - 0.5f * z;
    return (fabsf(z) < 1e-4f) ? small : big;
}

struct F5 { float dV, dn, dm, dh, dp; };

__device__ __forceinline__ F5 hh(float V, float n, float m, float h, float p, float I_in) {
    // VT = -60 folded into the offsets.
    float a_n = 0.16f  * efun(-0.2f  * (V + 45.0f));           // 0.032/0.2
    float a_m = 1.28f  * efun(-0.25f * (V + 47.0f));           // 0.32/0.25
    float b_n = 0.5f   * __expf((V + 50.0f) * -0.025f);        // 0.5*exp(-(V+50)/40)
    float a_h = 0.128f * __expf((V + 43.0f) * (-1.0f / 18.0f));

    // Shared exponential for beta_m and beta_h: z = 0.2(V+20), e = exp(z)
    //   beta_m = 1.4*efun(z) = 1.4 * z/(e-1)      (Taylor for |z|<1e-4)
    //   beta_h = 4/(1+exp(-z)) = 4e/(e+1) = 4 - 4/(e+1)
    // The "4 - 4*rcp(e+1)" form saturates correctly at e->inf (4) and e->0 (0),
    // unlike 4*e*rcp(e+1) which produces inf*0 = NaN at e=inf.
    float zb = 0.2f * (V + 20.0f);
    float eb = __expf(zb);
    float bm_big = zb * rcp_f(eb - 1.0f);
    float b_m = 1.4f * ((fabsf(zb) < 1e-4f) ? (1.0f - 0.5f * zb) : bm_big);
    float b_h = 4.0f - 4.0f * rcp_f(eb + 1.0f);

    float ekv = -107.0f - V;   // E_K - V
    float m3  = m * m * m;
    float n2  = n * n;

    F5 r;
    r.dV = 4.0f  * m3 * h * (53.0f - V)     // gbar_Na * m^3 * h * (E_Na - V)
         + 1.5f  * (n2 * n2) * ekv          // gbar_K * n^4 * (E_K - V)
         + 0.07f * p * ekv                  // gbar_M * p * (E_K - V)
         + 0.1f  * (-70.0f - V)             // g_leak * (E_leak - V)
         + I_in;                            // C_MEM = 1

    // dx = (a/(a+b) - x)*(a+b) == a - (a+b)*x  — rcp-free form
    float sn = a_n + b_n; r.dn = a_n - sn * n;
    float sm = a_m + b_m; r.dm = a_m - sm * m;
    float sh = a_h + b_h; r.dh = a_h - sh * h;

    // p gate: one exp. e5 = exp(0.05*v1); exp(-0.05*v1)=rcp(e5); exp(-0.1*v1)=rcp(e5)^2
    float v1   = V + 35.0f;
    float e5   = __expf(0.05f * v1);
    float re5  = rcp_f(e5);
    float pinf = rcp_f(1.0f + re5 * re5);
    float itau = (3.3f * e5 + re5) * (1.0f / 600.0f);
    r.dp = (pinf - p) * itau;
    return r;
}

__global__ __launch_bounds__(256) void hh_kernel(
    const int* __restrict__ tptr,
    const f32x4* __restrict__ V4, const f32x4* __restrict__ n4,
    const f32x4* __restrict__ m4, const f32x4* __restrict__ h4,
    const f32x4* __restrict__ p4,
    f32x4* __restrict__ out4, int nb4, float i_in_level)
{
    int i = blockIdx.x * blockDim.x + threadIdx.x;
    if (i >= nb4) return;

    // I_in = level if (t > I_ON=0 and t < I_OFF=inf) else 0
    float t = (float)(*tptr);
    float I_in = (t > 0.0f) ? i_in_level : 0.0f;

    f32x4 V = V4[i], n = n4[i], m = m4[i], h = h4[i], p = p4[i];

    F5 a = hh(V.x, n.x, m.x, h.x, p.x, I_in);
    F5 b = hh(V.y, n.y, m.y, h.y, p.y, I_in);
    F5 c = hh(V.z, n.z, m.z, h.z, p.z, I_in);
    F5 d = hh(V.w, n.w, m.w, h.w, p.w, I_in);

    f32x4 o;
    o.x = a.dV; o.y = b.dV; o.z = c.dV; o.w = d.dV;
    out4[i] = o;
    o.x = a.dn; o.y = b.dn; o.z = c.dn; o.w = d.dn;
    out4[i + nb4] = o;
    o.x = a.dm; o.y = b.dm; o.z = c.dm; o.w = d.dm;
    out4[i + 2 * nb4] = o;
    o.x = a.dh; o.y = b.dh; o.z = c.dh; o.w = d.dh;
    out4[i + 3 * nb4] = o;
    o.x = a.dp; o.y = b.dp; o.z = c.dp; o.w = d.dp;
    out4[i + 4 * nb4] = o;
}

} // anonymous namespace

extern "C" void kernel_launch(void* const* d_in, const int* in_sizes, int n_in,
                              void* d_out, int out_size, void* d_ws, size_t ws_size,
                              hipStream_t stream) {
    // setup_inputs order: t (int scalar), V, n, m, h, p  (each float32, B elems)
    const int*   t = (const int*)  d_in[0];
    const f32x4* V = (const f32x4*)d_in[1];
    const f32x4* n = (const f32x4*)d_in[2];
    const f32x4* m = (const f32x4*)d_in[3];
    const f32x4* h = (const f32x4*)d_in[4];
    const f32x4* p = (const f32x4*)d_in[5];

    int B   = in_sizes[1];     // 8388608, divisible by 4
    int nb4 = B / 4;

    // CURR_LEVEL / A_SOMA, A_SOMA = pi * (70e-4)^2
    float i_in = (float)(0.0005 / (3.141592653589793 * 70.0e-4 * 70.0e-4));

    int block = 256;
    int grid  = (nb4 + block - 1) / block;
    hh_kernel<<<grid, block, 0, stream>>>(t, V, n, m, h, p, (f32x4*)d_out, nb4, i_in);
}